// Round 15
// baseline (140.882 us; speedup 1.0000x reference)
//
#include <hip/hip_runtime.h>

#define T_LEN 2048
#define NSTATE 64
#define NCHUNK 32
#define CH_S 64       // stored steps per chunk
#define HF 32         // half of stored region (LDS depth per trajectory)
#define WARM 48       // warm-up steps (~8 x constraint length K=7)
#define RK 16         // renorm period = LLR log-batch size
#define ROWQ 20       // dwords per LDS row (16 data + 4 pad): 16B-aligned rows
#define TRAJ (NSTATE * ROWQ)   // dwords per trajectory buffer (5120 B)

// v_add_f32 with DPP-modified src.
template<int CTRL>
__device__ __forceinline__ float dpp_add(float v) {
    int r = __builtin_amdgcn_update_dpp(0, __float_as_int(v), CTRL, 0xF, 0xF, true);
    return v + __int_as_float(r);
}

// v_mov_b32_dpp quad_perm [1,0,3,2]: value of lane^1 — VALU, no DS op.
__device__ __forceinline__ float dpp_mov_xor1(float v) {
    return __int_as_float(__builtin_amdgcn_update_dpp(0, __float_as_int(v), 0xB1, 0xF, 0xF, true));
}

// Pure-DPP 64-lane sum to lane 63 (row_shr 1,2,4,8 + row_bcast15/31). Zero DS.
__device__ __forceinline__ float dpp_sum_to63(float v) {
    v = dpp_add<0x111>(v);
    v = dpp_add<0x112>(v);
    v = dpp_add<0x114>(v);
    v = dpp_add<0x118>(v);
    v = dpp_add<0x142>(v);
    v = dpp_add<0x143>(v);
    return v;
}

// Full-wave sum broadcast via v_readlane — zero DS ops.
__device__ __forceinline__ float wave_total(float v) {
    float s = dpp_sum_to63(v);
    return __int_as_float(__builtin_amdgcn_readlane(__float_as_int(s), 63));
}

// v + v[lane^1] via DPP quad_perm [1,0,3,2].
__device__ __forceinline__ float pair_sum_xor1(float v) {
    int r = __builtin_amdgcn_update_dpp(0, __float_as_int(v), 0xB1, 0xF, 0xF, true);
    return v + __int_as_float(r);
}

// raw bpermute: addrb is BYTE address (src_lane*4)
__device__ __forceinline__ float bperm(int addrb, float v) {
    return __int_as_float(__builtin_amdgcn_ds_bpermute(addrb, __float_as_int(v)));
}

// cheap fp32 -> bf16 (round-half-up)
__device__ __forceinline__ unsigned bf16_of(float f) {
    return (__float_as_uint(f) + 0x8000u) >> 16;
}
template<int HI>
__device__ __forceinline__ float bf16_half(unsigned w) {
    return __uint_as_float(HI ? (w & 0xffff0000u) : (w << 16));
}

// Stash lane-63 value of v into lane L of acc (readlane + predicated select).
__device__ __forceinline__ float stash63(float acc, float v, int L, int lane) {
    float bc = __int_as_float(__builtin_amdgcn_readlane(__float_as_int(v), 63));
    return (lane == L) ? bc : acc;
}

// GEN_POLY = ('1111001','1011011'), mu=6, NS=64.
// o0 parity mask 57, o1 mask 27. x_s = kE*(la + c0(s)*l0 + c1(s)*l1),
// gamma(s,0)=2^x, gamma(s,1)=2^-x, to(s,b)=(b<<5)|(s>>1), kE=0.5*log2(e).
//
// DUAL-CHAIN: each wave advances TWO independent recurrences (same chunk
// index, adjacent batches bA=2*bp, bB=2*bp+1 -> identical control flow).
// The two chains' bperm/DPP latencies interleave, halving per-chain stall
// exposure (rounds 9-14: single-chain is latency-bound at every geometry).
// LDS: 2 trajectories x 2 chains = 20 KiB -> 8 blocks/CU cap with exactly
// 16 blocks/CU of work = 2.0 clean generations.

// ---- fwd 16-step dual group. MODE: 0=light, 1=store alpha(H0), 2=heavy LLR(H1) ----
template<int MODE>
__device__ __forceinline__ void fwd_group2(float& sA, float& sB,
                                           const float* __restrict__ chpA,
                                           const float* __restrict__ chpB,
                                           const float* __restrict__ lapA,
                                           const float* __restrict__ lapB,
                                           unsigned* __restrict__ alds,       // [2][TRAJ]
                                           const unsigned* __restrict__ blds, // [2][TRAJ]
                                           float* __restrict__ outA,
                                           float* __restrict__ outB,
                                           int g, int t0, int lane,
                                           float kE, float k0, float k1,
                                           int fselb)
{
    float accA = 1.0f, accB = 1.0f;
    #pragma unroll
    for (int h = 0; h < 2; ++h) {
        const int gb = g + 8 * h;
        float4 ccA[4], aaA[2], ccB[4], aaB[2];
        {
            const float4* c4 = (const float4*)(chpA + 2 * gb);
            const float4* a4 = (const float4*)(lapA + gb);
            #pragma unroll
            for (int i = 0; i < 4; ++i) ccA[i] = c4[i];
            #pragma unroll
            for (int i = 0; i < 2; ++i) aaA[i] = a4[i];
        }
        {
            const float4* c4 = (const float4*)(chpB + 2 * gb);
            const float4* a4 = (const float4*)(lapB + gb);
            #pragma unroll
            for (int i = 0; i < 4; ++i) ccB[i] = c4[i];
            #pragma unroll
            for (int i = 0; i < 2; ++i) aaB[i] = a4[i];
        }
        uint4 bw0A, bw1A, bw0B, bw1B;
        if (MODE == 2) {
            const int off = (gb - t0 - HF) >> 1;
            bw0A = *(const uint4*)(blds + (lane >> 1) * ROWQ + off);
            bw1A = *(const uint4*)(blds + (32 + (lane >> 1)) * ROWQ + off);
            bw0B = *(const uint4*)(blds + TRAJ + (lane >> 1) * ROWQ + off);
            bw1B = *(const uint4*)(blds + TRAJ + (32 + (lane >> 1)) * ROWQ + off);
        }
        unsigned pkA[4], pkB[4];
        #pragma unroll
        for (int i = 0; i < 8; ++i) {
            // ---- chain A ----
            {
                float l0 = (i & 1) ? ccA[i >> 1].z : ccA[i >> 1].x;
                float l1 = (i & 1) ? ccA[i >> 1].w : ccA[i >> 1].y;
                float la = ((const float*)aaA)[i];
                if (MODE == 1) {
                    unsigned hs = bf16_of(sA);
                    if (i & 1) pkA[i >> 1] |= hs << 16; else pkA[i >> 1] = hs;
                }
                float x   = fmaf(la, kE, fmaf(l0, k0, l1 * k1));
                float g0v = exp2f(x);
                float g1v = __builtin_amdgcn_rcpf(g0v);
                float sg0 = sA * g0v;
                float sg1 = sA * g1v;
                if (MODE == 2) {
                    unsigned w0 = (&bw0A.x)[i >> 1];
                    unsigned w1 = (&bw1A.x)[i >> 1];
                    float b0v = (i & 1) ? bf16_half<1>(w0) : bf16_half<0>(w0);
                    float b1v = (i & 1) ? bf16_half<1>(w1) : bf16_half<0>(w1);
                    float na = dpp_sum_to63(sg0 * b0v);
                    float nb = dpp_sum_to63(sg1 * b1v);
                    accA = stash63(accA, na, 2 * (8 * h + i), lane);
                    accA = stash63(accA, nb, 2 * (8 * h + i) + 1, lane);
                }
                float s0 = pair_sum_xor1(sg0);
                float s1 = pair_sum_xor1(sg1);
                float v  = (lane & 1) ? s1 : s0;
                sA = bperm(fselb, v);
            }
            // ---- chain B ----
            {
                float l0 = (i & 1) ? ccB[i >> 1].z : ccB[i >> 1].x;
                float l1 = (i & 1) ? ccB[i >> 1].w : ccB[i >> 1].y;
                float la = ((const float*)aaB)[i];
                if (MODE == 1) {
                    unsigned hs = bf16_of(sB);
                    if (i & 1) pkB[i >> 1] |= hs << 16; else pkB[i >> 1] = hs;
                }
                float x   = fmaf(la, kE, fmaf(l0, k0, l1 * k1));
                float g0v = exp2f(x);
                float g1v = __builtin_amdgcn_rcpf(g0v);
                float sg0 = sB * g0v;
                float sg1 = sB * g1v;
                if (MODE == 2) {
                    unsigned w0 = (&bw0B.x)[i >> 1];
                    unsigned w1 = (&bw1B.x)[i >> 1];
                    float b0v = (i & 1) ? bf16_half<1>(w0) : bf16_half<0>(w0);
                    float b1v = (i & 1) ? bf16_half<1>(w1) : bf16_half<0>(w1);
                    float na = dpp_sum_to63(sg0 * b0v);
                    float nb = dpp_sum_to63(sg1 * b1v);
                    accB = stash63(accB, na, 2 * (8 * h + i), lane);
                    accB = stash63(accB, nb, 2 * (8 * h + i) + 1, lane);
                }
                float s0 = pair_sum_xor1(sg0);
                float s1 = pair_sum_xor1(sg1);
                float v  = (lane & 1) ? s1 : s0;
                sB = bperm(fselb, v);
            }
        }
        if (MODE == 1) {
            *(uint4*)(alds + lane * ROWQ + ((gb - t0) >> 1)) =
                make_uint4(pkA[0], pkA[1], pkA[2], pkA[3]);
            *(uint4*)(alds + TRAJ + lane * ROWQ + ((gb - t0) >> 1)) =
                make_uint4(pkB[0], pkB[1], pkB[2], pkB[3]);
        }
    }
    if (MODE == 2) {
        float lgA = __log2f(accA);
        float dlA = (lgA - dpp_mov_xor1(lgA)) * 0.6931471805599453f;
        float lgB = __log2f(accB);
        float dlB = (lgB - dpp_mov_xor1(lgB)) * 0.6931471805599453f;
        if (lane < 32 && !(lane & 1)) {
            outA[g + (lane >> 1)] = dlA;
            outB[g + (lane >> 1)] = dlB;
        }
    }
    float tA = wave_total(sA);
    sA = sA * __builtin_amdgcn_rcpf(tA);
    float tB = wave_total(sB);
    sB = sB * __builtin_amdgcn_rcpf(tB);
}

// ---- bwd 16-step dual group. MODE: 0=light, 1=store beta(H1), 2=heavy LLR(H0) ----
template<int MODE>
__device__ __forceinline__ void bwd_group2(float& sA, float& sB,
                                           const float* __restrict__ chpA,
                                           const float* __restrict__ chpB,
                                           const float* __restrict__ lapA,
                                           const float* __restrict__ lapB,
                                           const unsigned* __restrict__ alds, // [2][TRAJ]
                                           unsigned* __restrict__ blds,       // [2][TRAJ]
                                           float* __restrict__ outA,
                                           float* __restrict__ outB,
                                           int g, int t0, int lane,
                                           float kE, float k0, float k1,
                                           unsigned pmask, int bgb)
{
    const bool odd = (lane & 1);
    float accA = 1.0f, accB = 1.0f;
    #pragma unroll
    for (int h = 1; h >= 0; --h) {
        const int gb = g + 8 * h;
        float4 ccA[4], aaA[2], ccB[4], aaB[2];
        {
            const float4* c4 = (const float4*)(chpA + 2 * gb);
            const float4* a4 = (const float4*)(lapA + gb);
            #pragma unroll
            for (int i = 0; i < 4; ++i) ccA[i] = c4[i];
            #pragma unroll
            for (int i = 0; i < 2; ++i) aaA[i] = a4[i];
        }
        {
            const float4* c4 = (const float4*)(chpB + 2 * gb);
            const float4* a4 = (const float4*)(lapB + gb);
            #pragma unroll
            for (int i = 0; i < 4; ++i) ccB[i] = c4[i];
            #pragma unroll
            for (int i = 0; i < 2; ++i) aaB[i] = a4[i];
        }
        uint4 awA, awB;
        if (MODE == 2) {
            awA = *(const uint4*)(alds + lane * ROWQ + ((gb - t0) >> 1));
            awB = *(const uint4*)(alds + TRAJ + lane * ROWQ + ((gb - t0) >> 1));
        }
        unsigned pkA[4], pkB[4];
        #pragma unroll
        for (int i = 7; i >= 0; --i) {
            // ---- chain A ----
            {
                float l0 = (i & 1) ? ccA[i >> 1].z : ccA[i >> 1].x;
                float l1 = (i & 1) ? ccA[i >> 1].w : ccA[i >> 1].y;
                float la = ((const float*)aaA)[i];
                if (MODE == 1) {
                    // DESCENDING: odd i (first) initializes; even i ORs low half
                    unsigned hs = bf16_of(sA);
                    if (i & 1) pkA[i >> 1] = hs << 16; else pkA[i >> 1] |= hs;
                }
                float x  = fmaf(la, kE, fmaf(l0, k0, l1 * k1));
                float xg = __uint_as_float(__float_as_uint(x) ^ pmask);
                float ga  = exp2f(xg);
                float gb_ = __builtin_amdgcn_rcpf(ga);
                float a  = bperm(bgb, sA);
                float bb = dpp_mov_xor1(a);
                float u0 = ga * a;
                float u1 = gb_ * bb;
                if (MODE == 2) {
                    unsigned w = (&awA.x)[i >> 1];
                    float av = (i & 1) ? bf16_half<1>(w) : bf16_half<0>(w);
                    float ua = odd ? u1 : u0;
                    float ub = odd ? u0 : u1;
                    float na = dpp_sum_to63(av * ua);
                    float nb = dpp_sum_to63(av * ub);
                    accA = stash63(accA, na, 2 * (8 * h + i), lane);
                    accA = stash63(accA, nb, 2 * (8 * h + i) + 1, lane);
                }
                sA = u0 + u1;
            }
            // ---- chain B ----
            {
                float l0 = (i & 1) ? ccB[i >> 1].z : ccB[i >> 1].x;
                float l1 = (i & 1) ? ccB[i >> 1].w : ccB[i >> 1].y;
                float la = ((const float*)aaB)[i];
                if (MODE == 1) {
                    unsigned hs = bf16_of(sB);
                    if (i & 1) pkB[i >> 1] = hs << 16; else pkB[i >> 1] |= hs;
                }
                float x  = fmaf(la, kE, fmaf(l0, k0, l1 * k1));
                float xg = __uint_as_float(__float_as_uint(x) ^ pmask);
                float ga  = exp2f(xg);
                float gb_ = __builtin_amdgcn_rcpf(ga);
                float a  = bperm(bgb, sB);
                float bb = dpp_mov_xor1(a);
                float u0 = ga * a;
                float u1 = gb_ * bb;
                if (MODE == 2) {
                    unsigned w = (&awB.x)[i >> 1];
                    float av = (i & 1) ? bf16_half<1>(w) : bf16_half<0>(w);
                    float ua = odd ? u1 : u0;
                    float ub = odd ? u0 : u1;
                    float na = dpp_sum_to63(av * ua);
                    float nb = dpp_sum_to63(av * ub);
                    accB = stash63(accB, na, 2 * (8 * h + i), lane);
                    accB = stash63(accB, nb, 2 * (8 * h + i) + 1, lane);
                }
                sB = u0 + u1;
            }
        }
        if (MODE == 1) {
            *(uint4*)(blds + lane * ROWQ + ((gb - t0 - HF) >> 1)) =
                make_uint4(pkA[0], pkA[1], pkA[2], pkA[3]);
            *(uint4*)(blds + TRAJ + lane * ROWQ + ((gb - t0 - HF) >> 1)) =
                make_uint4(pkB[0], pkB[1], pkB[2], pkB[3]);
        }
    }
    if (MODE == 2) {
        float lgA = __log2f(accA);
        float dlA = (lgA - dpp_mov_xor1(lgA)) * 0.6931471805599453f;
        float lgB = __log2f(accB);
        float dlB = (lgB - dpp_mov_xor1(lgB)) * 0.6931471805599453f;
        if (lane < 32 && !(lane & 1)) {
            outA[g + (lane >> 1)] = dlA;
            outB[g + (lane >> 1)] = dlB;
        }
    }
    float tA = wave_total(sA);
    sA = sA * __builtin_amdgcn_rcpf(tA);
    float tB = wave_total(sB);
    sB = sB * __builtin_amdgcn_rcpf(tB);
}

// ---------------- Fused kernel: staggered half-chunks, dual-chain ----------------
__global__ __launch_bounds__(128, 4)
void bcjr_fused_kernel(const float* __restrict__ llr_ch,   // [B][2*T]
                       const float* __restrict__ llr_a,    // [B][T]
                       float* __restrict__ out)            // [B][T]
{
    __shared__ __align__(16) unsigned alds[2 * TRAJ];   // 10240 B: alpha(H0) x2
    __shared__ __align__(16) unsigned blds[2 * TRAJ];   // 10240 B: beta(H1)  x2

    const int lane  = threadIdx.x & 63;
    const int role  = threadIdx.x >> 6;
    const int unit  = blockIdx.x;
    const int chunk = unit & (NCHUNK - 1);
    const int bp    = unit >> 5;          // batch pair index
    const int bA    = 2 * bp;
    const int bB    = 2 * bp + 1;

    const float c0 = 1.0f - 2.0f * (float)(__popc(lane & 57) & 1);
    const float c1 = 1.0f - 2.0f * (float)(__popc(lane & 27) & 1);
    const float kE = 0.5f * 1.442695040888963f;
    const float k0 = kE * c0, k1 = kE * c1;

    const float* chpA = llr_ch + (size_t)bA * (2 * T_LEN);
    const float* chpB = llr_ch + (size_t)bB * (2 * T_LEN);
    const float* lapA = llr_a  + (size_t)bA * T_LEN;
    const float* lapB = llr_a  + (size_t)bB * T_LEN;
    float* outA = out + (size_t)bA * T_LEN;
    float* outB = out + (size_t)bB * T_LEN;
    const int t0 = chunk * CH_S;

    if (role == 0) {
        // ---- forward wave: two fwd chains ----
        const int fselb = (2 * (lane & 31) + (lane >> 5)) << 2;
        float init = (chunk == 0) ? ((lane == 0) ? 1.0f : 0.0f) : (1.0f / 64.0f);
        float sA = init, sB = init;
        const int ts = (chunk == 0) ? t0 : t0 - WARM;
        for (int g = ts; g < t0; g += RK)
            fwd_group2<0>(sA, sB, chpA, chpB, lapA, lapB, alds, blds, outA, outB, g, t0, lane, kE, k0, k1, fselb);
        for (int g = t0; g < t0 + HF; g += RK)
            fwd_group2<1>(sA, sB, chpA, chpB, lapA, lapB, alds, blds, outA, outB, g, t0, lane, kE, k0, k1, fselb);
        __syncthreads();   // alpha(H0) x2 published, beta(H1) x2 ready
        for (int g = t0 + HF; g < t0 + CH_S; g += RK)
            fwd_group2<2>(sA, sB, chpA, chpB, lapA, lapB, alds, blds, outA, outB, g, t0, lane, kE, k0, k1, fselb);
    } else {
        // ---- backward wave: two bwd chains ----
        const unsigned pmask = (unsigned)(lane & 1) << 31;
        const int bgb = ((lane >> 1) + ((lane & 1) << 5)) << 2;  // src lane * 4
        float sA = 1.0f / 64.0f, sB = 1.0f / 64.0f;
        const int te = (chunk == NCHUNK - 1) ? (t0 + CH_S) : (t0 + CH_S + WARM);
        for (int g = te - RK; g >= t0 + CH_S; g -= RK)
            bwd_group2<0>(sA, sB, chpA, chpB, lapA, lapB, alds, blds, outA, outB, g, t0, lane, kE, k0, k1, pmask, bgb);
        for (int g = t0 + CH_S - RK; g >= t0 + HF; g -= RK)
            bwd_group2<1>(sA, sB, chpA, chpB, lapA, lapB, alds, blds, outA, outB, g, t0, lane, kE, k0, k1, pmask, bgb);
        __syncthreads();   // beta(H1) x2 published, alpha(H0) x2 ready
        for (int g = t0 + HF - RK; g >= t0; g -= RK)
            bwd_group2<2>(sA, sB, chpA, chpB, lapA, lapB, alds, blds, outA, outB, g, t0, lane, kE, k0, k1, pmask, bgb);
    }
}

extern "C" void kernel_launch(void* const* d_in, const int* in_sizes, int n_in,
                              void* d_out, int out_size, void* d_ws, size_t ws_size,
                              hipStream_t stream) {
    const float* llr_ch = (const float*)d_in[0];
    const float* llr_a  = (const float*)d_in[1];
    float* out = (float*)d_out;

    int B = in_sizes[0] / (2 * T_LEN);   // 256
    (void)d_ws; (void)ws_size;

    int n_units = (B / 2) * NCHUNK;      // 4096 blocks (1 chunk x 2 batches each)
    hipLaunchKernelGGL(bcjr_fused_kernel, dim3(n_units), dim3(128), 0, stream,
                       llr_ch, llr_a, out);
}

// Round 16
// 127.279 us; speedup vs baseline: 1.1069x; 1.1069x over previous
//
#include <hip/hip_runtime.h>

#define T_LEN 2048
#define NSTATE 64
#define NCHUNK 16
#define CH_S 128      // stored steps per chunk
#define HF 64         // half of stored region (LDS depth per trajectory)
#define WARM 48       // warm-up steps (~8 x constraint length; verified r13, absmax unchanged)
#define RK 16         // renorm every 16 steps (scale cancels in LLR)

// v_add_f32 with DPP-modified src: single fused VALU instr, no DS op.
template<int CTRL>
__device__ __forceinline__ float dpp_add(float v) {
    int r = __builtin_amdgcn_update_dpp(0, __float_as_int(v), CTRL, 0xF, 0xF, true);
    return v + __int_as_float(r);
}

// v_mov_b32_dpp quad_perm [1,0,3,2]: value of lane^1 — VALU, no DS op.
__device__ __forceinline__ float dpp_mov_xor1(float v) {
    return __int_as_float(__builtin_amdgcn_update_dpp(0, __float_as_int(v), 0xB1, 0xF, 0xF, true));
}

// Pure-DPP 64-lane sum to lane 63 (row_shr 1,2,4,8 + row_bcast15/31). Zero DS.
__device__ __forceinline__ float dpp_sum_to63(float v) {
    v = dpp_add<0x111>(v);
    v = dpp_add<0x112>(v);
    v = dpp_add<0x114>(v);
    v = dpp_add<0x118>(v);
    v = dpp_add<0x142>(v);
    v = dpp_add<0x143>(v);
    return v;
}

// Full-wave sum broadcast via v_readlane — zero DS ops.
__device__ __forceinline__ float wave_total(float v) {
    float s = dpp_sum_to63(v);
    return __int_as_float(__builtin_amdgcn_readlane(__float_as_int(s), 63));
}

// v + v[lane^1] via DPP quad_perm [1,0,3,2].
__device__ __forceinline__ float pair_sum_xor1(float v) {
    int r = __builtin_amdgcn_update_dpp(0, __float_as_int(v), 0xB1, 0xF, 0xF, true);
    return v + __int_as_float(r);
}

// raw bpermute: addrb is BYTE address (src_lane*4)
__device__ __forceinline__ float bperm(int addrb, float v) {
    return __int_as_float(__builtin_amdgcn_ds_bpermute(addrb, __float_as_int(v)));
}

// cheap fp32 -> bf16 (round-half-up)
__device__ __forceinline__ unsigned bf16_of(float f) {
    return (__float_as_uint(f) + 0x8000u) >> 16;
}
// unpack bf16 half (compile-time hi) of a packed dword
template<int HI>
__device__ __forceinline__ float bf16_half(unsigned w) {
    return __uint_as_float(HI ? (w & 0xffff0000u) : (w << 16));
}

// LDS addressing (r13-verified): row = state (64 rows) x 32 dwords (64 bf16
// cols), NO pad. 16B-chunk XOR swizzle (chunk ^ row&7) spreads rows across
// bank groups at 8192 B/trajectory -> 16 KiB/block -> 10 blocks/CU.
__device__ __forceinline__ int swz(int row, int cc) {
    return row * 32 + (((cc ^ row) & 7) << 2);
}

// GEN_POLY = ('1111001','1011011'), mu=6, NS=64.
// o0 parity mask 57, o1 mask 27. x_s = kE*(la + c0(s)*l0 + c1(s)*l1),
// gamma(s,0)=2^x, gamma(s,1)=2^-x, to(s,b)=(b<<5)|(s>>1), kE=0.5*log2(e).
//
// Round 16 = r9's verified per-step-log heavy step + r13's verified WARM=48
// and swizzled 16 KiB layout. (r13's stash-based batched log was identified
// as a pessimization: readlane->SGPR->cndmask chains stall VALU<->SALU; the
// two pipelined v_log_f32 per heavy step are cheaper.)

// ---- fwd 16-step group. MODE: 0=light, 1=store alpha(H0), 2=heavy LLR(H1) ----
template<int MODE>
__device__ __forceinline__ float fwd_group(float state,
                                           const float* __restrict__ chp,
                                           const float* __restrict__ lap,
                                           unsigned* __restrict__ alds,
                                           const unsigned* __restrict__ blds,
                                           float* __restrict__ outp,
                                           int g, int t0, int lane,
                                           float kE, float k0, float k1,
                                           int fselb)
{
    #pragma unroll
    for (int h = 0; h < 2; ++h) {
        const int gb = g + 8 * h;
        const float4* c4 = (const float4*)(chp + 2 * gb);
        const float4* a4 = (const float4*)(lap + gb);
        float4 cc[4], aa[2];
        #pragma unroll
        for (int i = 0; i < 4; ++i) cc[i] = c4[i];
        #pragma unroll
        for (int i = 0; i < 2; ++i) aa[i] = a4[i];
        uint4 bw0, bw1;
        if (MODE == 2) {
            // beta_{t+1} for the 8 steps: 2 swizzled vector reads (rows m, 32+m)
            const int ch = (gb - t0 - HF) >> 3;
            bw0 = *(const uint4*)(blds + swz(lane >> 1, ch));
            bw1 = *(const uint4*)(blds + swz(32 + (lane >> 1), ch));
        }
        unsigned pk[4];
        #pragma unroll
        for (int i = 0; i < 8; ++i) {
            float l0 = (i & 1) ? cc[i >> 1].z : cc[i >> 1].x;
            float l1 = (i & 1) ? cc[i >> 1].w : cc[i >> 1].y;
            float la = ((const float*)aa)[i];
            if (MODE == 1) {                       // ascending: even i first (=), odd ORs
                unsigned hs = bf16_of(state);
                if (i & 1) pk[i >> 1] |= hs << 16; else pk[i >> 1] = hs;
            }
            float x   = fmaf(la, kE, fmaf(l0, k0, l1 * k1));
            float g0v = exp2f(x);
            float g1v = __builtin_amdgcn_rcpf(g0v);
            float sg0 = state * g0v;               // alpha_t[s]*gamma0(s)
            float sg1 = state * g1v;               // alpha_t[s]*gamma1(s)
            if (MODE == 2) {
                unsigned w0 = (&bw0.x)[i >> 1];
                unsigned w1 = (&bw1.x)[i >> 1];
                float b0v = (i & 1) ? bf16_half<1>(w0) : bf16_half<0>(w0);
                float b1v = (i & 1) ? bf16_half<1>(w1) : bf16_half<0>(w1);
                float na = dpp_sum_to63(sg0 * b0v);     // n0 total -> lane 63
                float nb = dpp_sum_to63(sg1 * b1v);     // n1 total -> lane 63
                if (lane == 63)
                    outp[gb + i] = (__log2f(na) - __log2f(nb)) * 0.6931471805599453f;
            }
            float s0 = pair_sum_xor1(sg0);
            float s1 = pair_sum_xor1(sg1);
            float v  = (lane & 1) ? s1 : s0;       // even lane: s0, odd: s1
            state = bperm(fselb, v);               // dest j <- lane 2(j&31)+(j>>5)
        }
        if (MODE == 1)
            *(uint4*)(alds + swz(lane, (gb - t0) >> 3)) =
                make_uint4(pk[0], pk[1], pk[2], pk[3]);
    }
    float s = wave_total(state);
    return state * __builtin_amdgcn_rcpf(s);
}

// ---- bwd 16-step group. MODE: 0=light, 1=store beta(H1), 2=heavy LLR(H0) ----
template<int MODE>
__device__ __forceinline__ float bwd_group(float state,
                                           const float* __restrict__ chp,
                                           const float* __restrict__ lap,
                                           const unsigned* __restrict__ alds,
                                           unsigned* __restrict__ blds,
                                           float* __restrict__ outp,
                                           int g, int t0, int lane,
                                           float kE, float k0, float k1,
                                           unsigned pmask, int bgb)
{
    const bool odd = (lane & 1);
    #pragma unroll
    for (int h = 1; h >= 0; --h) {
        const int gb = g + 8 * h;
        const float4* c4 = (const float4*)(chp + 2 * gb);
        const float4* a4 = (const float4*)(lap + gb);
        float4 cc[4], aa[2];
        #pragma unroll
        for (int i = 0; i < 4; ++i) cc[i] = c4[i];
        #pragma unroll
        for (int i = 0; i < 2; ++i) aa[i] = a4[i];
        uint4 aw;
        if (MODE == 2)   // alpha_t for the 8 steps: ONE swizzled vector read
            aw = *(const uint4*)(alds + swz(lane, (gb - t0) >> 3));
        unsigned pk[4];
        #pragma unroll
        for (int i = 7; i >= 0; --i) {
            float l0 = (i & 1) ? cc[i >> 1].z : cc[i >> 1].x;
            float l1 = (i & 1) ? cc[i >> 1].w : cc[i >> 1].y;
            float la = ((const float*)aa)[i];
            if (MODE == 1) {
                // DESCENDING loop: odd i (first) initializes; even i ORs low half
                unsigned hs = bf16_of(state);
                if (i & 1) pk[i >> 1] = hs << 16; else pk[i >> 1] |= hs;
            }
            float x  = fmaf(la, kE, fmaf(l0, k0, l1 * k1));
            float xg = __uint_as_float(__float_as_uint(x) ^ pmask);
            float ga  = exp2f(xg);                     // even: gamma0, odd: gamma1
            float gb_ = __builtin_amdgcn_rcpf(ga);     // even: gamma1, odd: gamma0
            float a  = bperm(bgb, state);              // even: beta[m], odd: beta[m+32]
            float bb = dpp_mov_xor1(a);                // partner value
            float u0 = ga * a;
            float u1 = gb_ * bb;
            if (MODE == 2) {
                unsigned w = (&aw.x)[i >> 1];
                float av = (i & 1) ? bf16_half<1>(w) : bf16_half<0>(w);
                float ua = odd ? u1 : u0;              // gamma0*beta[to0(s)]
                float ub = odd ? u0 : u1;              // gamma1*beta[to1(s)]
                float na = dpp_sum_to63(av * ua);      // n0 total -> lane 63
                float nb = dpp_sum_to63(av * ub);      // n1 total -> lane 63
                if (lane == 63)
                    outp[gb + i] = (__log2f(na) - __log2f(nb)) * 0.6931471805599453f;
            }
            state = u0 + u1;                           // beta_t
        }
        if (MODE == 1)
            *(uint4*)(blds + swz(lane, (gb - t0 - HF) >> 3)) =
                make_uint4(pk[0], pk[1], pk[2], pk[3]);
    }
    float s = wave_total(state);
    return state * __builtin_amdgcn_rcpf(s);
}

// ---------------- Fused kernel: staggered half-chunks ----------------
// Segment A (balanced, 112 steps each): fwd = warm + stored-H0 (alpha->LDS);
//                                       bwd = warm + stored-H1 (beta->LDS).
// Barrier.
// Segment B (balanced, 64 steps each):  fwd sweeps H1 w/ inline LLR (beta
//                                       from LDS); bwd sweeps H0 likewise.
// 16 KiB swizzled LDS -> 10 blocks/CU cap.
__global__ __launch_bounds__(128, 5)
void bcjr_fused_kernel(const float* __restrict__ llr_ch,   // [B][2*T]
                       const float* __restrict__ llr_a,    // [B][T]
                       float* __restrict__ out)            // [B][T]
{
    __shared__ __align__(16) unsigned alds[NSTATE * 32];   // 8192 B: alpha(H0)
    __shared__ __align__(16) unsigned blds[NSTATE * 32];   // 8192 B: beta(H1)

    const int lane  = threadIdx.x & 63;
    const int role  = threadIdx.x >> 6;
    const int unit  = blockIdx.x;
    const int chunk = unit & (NCHUNK - 1);
    const int b     = unit >> 4;

    const float c0 = 1.0f - 2.0f * (float)(__popc(lane & 57) & 1);
    const float c1 = 1.0f - 2.0f * (float)(__popc(lane & 27) & 1);
    const float kE = 0.5f * 1.442695040888963f;
    const float k0 = kE * c0, k1 = kE * c1;

    const float* chp = llr_ch + (size_t)b * (2 * T_LEN);
    const float* lap = llr_a  + (size_t)b * T_LEN;
    float* outp = out + (size_t)b * T_LEN;
    const int t0 = chunk * CH_S;

    if (role == 0) {
        // ---- forward wave ----
        const int fselb = (2 * (lane & 31) + (lane >> 5)) << 2;
        float state = (chunk == 0) ? ((lane == 0) ? 1.0f : 0.0f) : (1.0f / 64.0f);
        const int ts = (chunk == 0) ? t0 : t0 - WARM;
        for (int g = ts; g < t0; g += RK)
            state = fwd_group<0>(state, chp, lap, alds, blds, outp, g, t0, lane, kE, k0, k1, fselb);
        for (int g = t0; g < t0 + HF; g += RK)
            state = fwd_group<1>(state, chp, lap, alds, blds, outp, g, t0, lane, kE, k0, k1, fselb);
        __syncthreads();   // alpha(H0) published, beta(H1) ready
        for (int g = t0 + HF; g < t0 + CH_S; g += RK)
            state = fwd_group<2>(state, chp, lap, alds, blds, outp, g, t0, lane, kE, k0, k1, fselb);
    } else {
        // ---- backward wave ----
        const unsigned pmask = (unsigned)(lane & 1) << 31;
        const int bgb = ((lane >> 1) + ((lane & 1) << 5)) << 2;  // src lane * 4
        float state = 1.0f / 64.0f;          // exact beta_T for the last chunk
        const int te = (chunk == NCHUNK - 1) ? (t0 + CH_S) : (t0 + CH_S + WARM);
        for (int g = te - RK; g >= t0 + CH_S; g -= RK)
            state = bwd_group<0>(state, chp, lap, alds, blds, outp, g, t0, lane, kE, k0, k1, pmask, bgb);
        for (int g = t0 + CH_S - RK; g >= t0 + HF; g -= RK)
            state = bwd_group<1>(state, chp, lap, alds, blds, outp, g, t0, lane, kE, k0, k1, pmask, bgb);
        __syncthreads();   // beta(H1) published, alpha(H0) ready
        for (int g = t0 + HF - RK; g >= t0; g -= RK)
            state = bwd_group<2>(state, chp, lap, alds, blds, outp, g, t0, lane, kE, k0, k1, pmask, bgb);
    }
}

extern "C" void kernel_launch(void* const* d_in, const int* in_sizes, int n_in,
                              void* d_out, int out_size, void* d_ws, size_t ws_size,
                              hipStream_t stream) {
    const float* llr_ch = (const float*)d_in[0];
    const float* llr_a  = (const float*)d_in[1];
    float* out = (float*)d_out;

    int B = in_sizes[0] / (2 * T_LEN);   // 256
    (void)d_ws; (void)ws_size;

    int n_units = B * NCHUNK;            // 4096 blocks (1 chunk each, 2 waves)
    hipLaunchKernelGGL(bcjr_fused_kernel, dim3(n_units), dim3(128), 0, stream,
                       llr_ch, llr_a, out);
}